// Round 4
// baseline (239.056 us; speedup 1.0000x reference)
//
#include <hip/hip_runtime.h>
#include <hip/hip_bf16.h>

#define S_LEN 4096
#define HID   768
#define NH    12
#define HD    64

typedef __attribute__((ext_vector_type(8))) __bf16 bf16x8;
typedef __attribute__((ext_vector_type(4))) float  f32x4;

// round-to-nearest-even fp32 -> bf16
__device__ __forceinline__ unsigned short f2bf(float f) {
  union { float f; unsigned u; } v; v.f = f;
  unsigned r = v.u + 0x7fffu + ((v.u >> 16) & 1u);
  return (unsigned short)(r >> 16);
}

// pack two fp32 -> bf16x2 (low = first arg)
__device__ __forceinline__ unsigned pk2bf(float lo, float hi) {
  __hip_bfloat162 h = __float22bfloat162_rn(make_float2(lo, hi));
  union { __hip_bfloat162 h; unsigned u; } v; v.h = h;
  return v.u;
}

// ---------------------------------------------------------------------------
// Prep 1: X fp32 -> bf16
// ---------------------------------------------------------------------------
__global__ __launch_bounds__(256) void conv_x(const float* __restrict__ X,
                                              unsigned short* __restrict__ Xb)
{
  const int i = blockIdx.x * 256 + threadIdx.x;
  const float4 v = ((const float4*)X)[i];
  ushort4 o;
  o.x = f2bf(v.x); o.y = f2bf(v.y); o.z = f2bf(v.z); o.w = f2bf(v.w);
  ((ushort4*)Xb)[i] = o;
}

// ---------------------------------------------------------------------------
// Prep 2: W [k][n] fp32 -> Wt [n][k] bf16 (z = q/k/v)
// ---------------------------------------------------------------------------
__global__ __launch_bounds__(256) void conv_wt(
    const float* __restrict__ Wq, const float* __restrict__ Wk, const float* __restrict__ Wv,
    unsigned short* __restrict__ Wt)
{
  const int z = blockIdx.z;
  const float* W = (z == 0) ? Wq : (z == 1) ? Wk : Wv;
  unsigned short* O = Wt + (size_t)z * HID * HID;
  const int k0 = blockIdx.x * 64, n0 = blockIdx.y * 64;
  __shared__ unsigned short T[64][72];
  const int tid = threadIdx.x;
  #pragma unroll
  for (int i = tid; i < 512; i += 256) {
    const int kr = i >> 3, c8 = (i & 7) * 8;
    const float4 a = *(const float4*)&W[(size_t)(k0 + kr) * HID + n0 + c8];
    const float4 b = *(const float4*)&W[(size_t)(k0 + kr) * HID + n0 + c8 + 4];
    T[kr][c8 + 0] = f2bf(a.x); T[kr][c8 + 1] = f2bf(a.y);
    T[kr][c8 + 2] = f2bf(a.z); T[kr][c8 + 3] = f2bf(a.w);
    T[kr][c8 + 4] = f2bf(b.x); T[kr][c8 + 5] = f2bf(b.y);
    T[kr][c8 + 6] = f2bf(b.z); T[kr][c8 + 7] = f2bf(b.w);
  }
  __syncthreads();
  #pragma unroll
  for (int i = tid; i < 512; i += 256) {
    const int nr = i >> 3, c8 = (i & 7) * 8;
    ushort4 lo, hi;
    lo.x = T[c8 + 0][nr]; lo.y = T[c8 + 1][nr]; lo.z = T[c8 + 2][nr]; lo.w = T[c8 + 3][nr];
    hi.x = T[c8 + 4][nr]; hi.y = T[c8 + 5][nr]; hi.z = T[c8 + 6][nr]; hi.w = T[c8 + 7][nr];
    ushort4* dst = (ushort4*)&O[(size_t)(n0 + nr) * HID + k0 + c8];
    dst[0] = lo; dst[1] = hi;
  }
}

// ---------------------------------------------------------------------------
// Kernel 1: QKV projection. 64x64 tile, BK=64, register prefetch, XOR-swizzled
// unpadded LDS. Q pre-scaled by 0.125*log2(e) (exp2 softmax downstream).
// Epilogue restages C through LDS -> fully coalesced b128 global stores.
// V written as [h][d][s] with within-64-block permutation
// tau(k) = (k>>5)*32 + (k&15)*2 + ((k>>4)&1)  (matches attn's P layout).
// ---------------------------------------------------------------------------
__global__ __launch_bounds__(256) void qkv_proj(
    const unsigned short* __restrict__ Xb, const unsigned short* __restrict__ Wt,
    const float* __restrict__ bq, const float* __restrict__ bk, const float* __restrict__ bv,
    unsigned short* __restrict__ Qo, unsigned short* __restrict__ Ko, unsigned short* __restrict__ Vo)
{
  const int which = blockIdx.z;
  const unsigned short* W = Wt + (size_t)which * HID * HID;   // [n][k]
  const float* bias = (which == 0) ? bq : (which == 1) ? bk : bv;
  unsigned short* Out = (which == 0) ? Qo : (which == 1) ? Ko : Vo;

  const int tid  = threadIdx.x;
  const int wave = tid >> 6;
  const int lane = tid & 63;
  const int g = lane >> 4, c = lane & 15;
  const int h  = blockIdx.x;          // head == n-tile
  const int n0 = h * 64;
  const int m0 = blockIdx.y * 64;

  __shared__ unsigned short Xl[4096];     // [m][k] swizzled, stride 64
  __shared__ unsigned short Wl[4096];     // [n][k] swizzled
  __shared__ unsigned short Sm[64 * 72];  // epilogue restage

  f32x4 acc[4] = {{0.f,0.f,0.f,0.f},{0.f,0.f,0.f,0.f},{0.f,0.f,0.f,0.f},{0.f,0.f,0.f,0.f}};

  bf16x8 rx[2], rw[2];
  #pragma unroll
  for (int j = 0; j < 2; ++j) {
    const int id = tid + 256 * j, row = id >> 3, c8 = (id & 7) * 8;
    rx[j] = *(const bf16x8*)&Xb[(size_t)(m0 + row) * HID + c8];
    rw[j] = *(const bf16x8*)&W [(size_t)(n0 + row) * HID + c8];
  }

  const int swz = (c & 7) * 8;   // frag-read column swizzle (row % 8 == c % 8)

  for (int k0 = 0; k0 < HID; k0 += 64) {
    __syncthreads();
    #pragma unroll
    for (int j = 0; j < 2; ++j) {
      const int id = tid + 256 * j, row = id >> 3, c8 = (id & 7) * 8;
      const int sc8 = c8 ^ ((row & 7) * 8);
      *(bf16x8*)&Xl[row * 64 + sc8] = rx[j];
      *(bf16x8*)&Wl[row * 64 + sc8] = rw[j];
    }
    __syncthreads();

    if (k0 + 64 < HID) {
      const int kk = k0 + 64;
      #pragma unroll
      for (int j = 0; j < 2; ++j) {
        const int id = tid + 256 * j, row = id >> 3, c8 = (id & 7) * 8;
        rx[j] = *(const bf16x8*)&Xb[(size_t)(m0 + row) * HID + kk + c8];
        rw[j] = *(const bf16x8*)&W [(size_t)(n0 + row) * HID + kk + c8];
      }
    }

    const bf16x8 a0 = *(const bf16x8*)&Xl[(wave * 16 + c) * 64 + ((g * 8) ^ swz)];
    const bf16x8 a1 = *(const bf16x8*)&Xl[(wave * 16 + c) * 64 + ((32 + g * 8) ^ swz)];
    #pragma unroll
    for (int nt = 0; nt < 4; ++nt) {
      const bf16x8 b0 = *(const bf16x8*)&Wl[(nt * 16 + c) * 64 + ((g * 8) ^ swz)];
      const bf16x8 b1 = *(const bf16x8*)&Wl[(nt * 16 + c) * 64 + ((32 + g * 8) ^ swz)];
      acc[nt] = __builtin_amdgcn_mfma_f32_16x16x32_bf16(a0, b0, acc[nt], 0, 0, 0);
      acc[nt] = __builtin_amdgcn_mfma_f32_16x16x32_bf16(a1, b1, acc[nt], 0, 0, 0);
    }
  }

  // epilogue: bias + scale, restage to LDS, coalesced b128 stores
  const float qsc = (which == 0) ? 0.1803368782f : 1.0f;   // 0.125 * log2(e)
  __syncthreads();   // Xl/Wl reads done; Sm may alias nothing but keep order clean
  #pragma unroll
  for (int nt = 0; nt < 4; ++nt) {
    const int n = n0 + nt * 16 + c;
    const float bv_ = bias[n];
    #pragma unroll
    for (int r = 0; r < 4; ++r) {
      const unsigned short val = f2bf((acc[nt][r] + bv_) * qsc);
      if (which == 2) {
        // Sm[d][tau(s_local)] ; s_local = wave*16 + 4g + r
        const int pos = (wave >> 1) * 32 + (4 * g + r) * 2 + (wave & 1);
        Sm[(nt * 16 + c) * 72 + pos] = val;
      } else {
        Sm[(wave * 16 + 4 * g + r) * 72 + nt * 16 + c] = val;
      }
    }
  }
  __syncthreads();
  #pragma unroll
  for (int jj = 0; jj < 2; ++jj) {
    const int j = tid + 256 * jj, row = j >> 3, off = (j & 7) * 8;
    const bf16x8 v = *(const bf16x8*)&Sm[row * 72 + off];
    if (which == 2)
      *(bf16x8*)&Out[((size_t)h * HD + row) * S_LEN + m0 + off] = v;   // [h][d][s-perm]
    else
      *(bf16x8*)&Out[((size_t)h * S_LEN + m0 + row) * HD + off] = v;   // [h][s][d]
  }
}

// ---------------------------------------------------------------------------
// Kernel 2: attention. WG = 2 waves x 64 q = 128 queries; KV-split 2
// (each WG: 2048 keys, 32 tiles). No-max softmax via exp2 (Q pre-scaled by
// log2e/8). P packed b32 with permutation tau; denominator via ones-column
// MFMA; partials atomically added (2 contributions/elem - deterministic).
// ---------------------------------------------------------------------------
__global__ __launch_bounds__(128, 2) void attn(
    const unsigned short* __restrict__ Q, const unsigned short* __restrict__ K,
    const unsigned short* __restrict__ Vp,   // [h][d][s-perm]
    float* __restrict__ O, float* __restrict__ L)
{
  const int qt = blockIdx.x;   // 0..31
  const int h  = blockIdx.y;   // 0..11
  const int sp = blockIdx.z;   // 0..1
  const int tid  = threadIdx.x;
  const int wave = tid >> 6;
  const int lane = tid & 63;
  const int g = lane >> 4, c = lane & 15;
  const int q0 = qt * 128;
  const int k_base = sp * 2048;

  __shared__ unsigned short Kl[4096];      // [key][d] swizzled
  __shared__ unsigned short Vt[4096];      // [d][key-perm] swizzled
  __shared__ unsigned short Pl[2][4096];   // per-wave P [q][key-perm] swizzled

  // Q A-frags straight from global (4 strips x 2 k-halves)
  bf16x8 aq[4][2];
  #pragma unroll
  for (int s = 0; s < 4; ++s) {
    const size_t qrow = (size_t)h * S_LEN + q0 + wave * 64 + s * 16 + c;
    aq[s][0] = *(const bf16x8*)&Q[qrow * HD + g * 8];
    aq[s][1] = *(const bf16x8*)&Q[qrow * HD + 32 + g * 8];
  }

  bf16x8 bones;   // B column 0 = 1.0 -> C[:,0] = row sums
  {
    const unsigned short one_bf = (c == 0) ? 0x3F80u : 0u;
    #pragma unroll
    for (int j = 0; j < 8; ++j) ((unsigned short*)&bones)[j] = one_bf;
  }

  f32x4 o[4][4];
  #pragma unroll
  for (int s = 0; s < 4; ++s)
    #pragma unroll
    for (int nt = 0; nt < 4; ++nt) o[s][nt] = (f32x4){0.f, 0.f, 0.f, 0.f};
  f32x4 lacc[4] = {{0.f,0.f,0.f,0.f},{0.f,0.f,0.f,0.f},{0.f,0.f,0.f,0.f},{0.f,0.f,0.f,0.f}};

  const int swz = (c & 7) * 8;
  unsigned short* P = Pl[wave];

  for (int kt = 0; kt < 32; ++kt) {
    __syncthreads();   // previous tile's frag reads done
    #pragma unroll
    for (int jj = 0; jj < 4; ++jj) {
      const int j = tid + 128 * jj, row = j >> 3, c8 = (j & 7) * 8;
      const int sc8 = c8 ^ ((row & 7) * 8);
      *(bf16x8*)&Kl[row * 64 + sc8] =
          *(const bf16x8*)&K[((size_t)h * S_LEN + k_base + kt * 64 + row) * HD + c8];
      *(bf16x8*)&Vt[row * 64 + sc8] =
          *(const bf16x8*)&Vp[((size_t)h * HD + row) * S_LEN + k_base + kt * 64 + c8];
    }
    __syncthreads();

    // QK^T in two nt-pairs (limits live score regs); exp2 + b32 pack to P
    #pragma unroll
    for (int pr = 0; pr < 2; ++pr) {
      f32x4 sc[2][4];
      #pragma unroll
      for (int ntl = 0; ntl < 2; ++ntl) {
        const int nt = pr * 2 + ntl;
        const bf16x8 b0 = *(const bf16x8*)&Kl[(nt * 16 + c) * 64 + ((g * 8) ^ swz)];
        const bf16x8 b1 = *(const bf16x8*)&Kl[(nt * 16 + c) * 64 + ((32 + g * 8) ^ swz)];
        #pragma unroll
        for (int s = 0; s < 4; ++s) {
          f32x4 z = {0.f, 0.f, 0.f, 0.f};
          z = __builtin_amdgcn_mfma_f32_16x16x32_bf16(aq[s][0], b0, z, 0, 0, 0);
          z = __builtin_amdgcn_mfma_f32_16x16x32_bf16(aq[s][1], b1, z, 0, 0, 0);
          sc[ntl][s] = z;
        }
      }
      #pragma unroll
      for (int s = 0; s < 4; ++s) {
        #pragma unroll
        for (int r = 0; r < 4; ++r) {
          const unsigned u = pk2bf(exp2f(sc[0][s][r]), exp2f(sc[1][s][r]));
          const int row = s * 16 + 4 * g + r;
          const int col = pr * 32 + 2 * c;
          *(unsigned*)&P[row * 64 + (col ^ ((row & 7) * 8))] = u;
        }
      }
    }

    // P A-frags (same wave wrote them; lgkmcnt ordering by compiler)
    bf16x8 ap[4][2];
    #pragma unroll
    for (int s = 0; s < 4; ++s) {
      ap[s][0] = *(const bf16x8*)&P[(s * 16 + c) * 64 + ((g * 8) ^ swz)];
      ap[s][1] = *(const bf16x8*)&P[(s * 16 + c) * 64 + ((32 + g * 8) ^ swz)];
    }
    #pragma unroll
    for (int nt = 0; nt < 4; ++nt) {
      const bf16x8 b0 = *(const bf16x8*)&Vt[(nt * 16 + c) * 64 + ((g * 8) ^ swz)];
      const bf16x8 b1 = *(const bf16x8*)&Vt[(nt * 16 + c) * 64 + ((32 + g * 8) ^ swz)];
      #pragma unroll
      for (int s = 0; s < 4; ++s) {
        o[s][nt] = __builtin_amdgcn_mfma_f32_16x16x32_bf16(ap[s][0], b0, o[s][nt], 0, 0, 0);
        o[s][nt] = __builtin_amdgcn_mfma_f32_16x16x32_bf16(ap[s][1], b1, o[s][nt], 0, 0, 0);
      }
    }
    #pragma unroll
    for (int s = 0; s < 4; ++s) {
      lacc[s] = __builtin_amdgcn_mfma_f32_16x16x32_bf16(ap[s][0], bones, lacc[s], 0, 0, 0);
      lacc[s] = __builtin_amdgcn_mfma_f32_16x16x32_bf16(ap[s][1], bones, lacc[s], 0, 0, 0);
    }
  }

  // epilogue: accumulate partials (exactly 2 contributions per element)
  #pragma unroll
  for (int s = 0; s < 4; ++s) {
    const int row = q0 + wave * 64 + s * 16 + 4 * g;
    #pragma unroll
    for (int nt = 0; nt < 4; ++nt) {
      #pragma unroll
      for (int r = 0; r < 4; ++r)
        atomicAdd(&O[(size_t)(row + r) * HID + h * HD + nt * 16 + c], o[s][nt][r]);
    }
  }
  if (c == 0) {
    #pragma unroll
    for (int s = 0; s < 4; ++s)
      #pragma unroll
      for (int r = 0; r < 4; ++r)
        atomicAdd(&L[h * S_LEN + q0 + wave * 64 + s * 16 + 4 * g + r], lacc[s][r]);
  }
}

// ---------------------------------------------------------------------------
// Kernel 3: normalize O by softmax denominator
// ---------------------------------------------------------------------------
__global__ __launch_bounds__(256) void normalize(float* __restrict__ O,
                                                 const float* __restrict__ L)
{
  const int i = blockIdx.x * 256 + threadIdx.x;
  float4 v = ((const float4*)O)[i];
  const int idx4 = i * 4;
  const int row = idx4 / HID;
  const int h   = (idx4 % HID) >> 6;
  const float inv = 1.0f / L[h * S_LEN + row];
  v.x *= inv; v.y *= inv; v.z *= inv; v.w *= inv;
  ((float4*)O)[i] = v;
}

// ---------------------------------------------------------------------------
extern "C" void kernel_launch(void* const* d_in, const int* in_sizes, int n_in,
                              void* d_out, int out_size, void* d_ws, size_t ws_size,
                              hipStream_t stream) {
  const float* X  = (const float*)d_in[0];
  const float* Wq = (const float*)d_in[1];
  const float* bq = (const float*)d_in[2];
  const float* Wk = (const float*)d_in[3];
  const float* bk = (const float*)d_in[4];
  const float* Wv = (const float*)d_in[5];
  const float* bv = (const float*)d_in[6];

  unsigned short* Xb = (unsigned short*)d_ws;
  unsigned short* Wt = Xb + (size_t)S_LEN * HID;
  unsigned short* Qb = Wt + (size_t)3 * HID * HID;
  unsigned short* Kb = Qb + (size_t)NH * S_LEN * HD;
  unsigned short* Vb = Kb + (size_t)NH * S_LEN * HD;
  float* L = (float*)(Vb + (size_t)NH * S_LEN * HD);
  float* O = (float*)d_out;

  hipMemsetAsync(O, 0, (size_t)S_LEN * HID * sizeof(float), stream);
  hipMemsetAsync(L, 0, (size_t)NH * S_LEN * sizeof(float), stream);

  conv_x <<<dim3((S_LEN * HID / 4) / 256), 256, 0, stream>>>(X, Xb);
  conv_wt<<<dim3(12, 12, 3), 256, 0, stream>>>(Wq, Wk, Wv, Wt);
  qkv_proj<<<dim3(12, 64, 3), 256, 0, stream>>>(Xb, Wt, bq, bk, bv, Qb, Kb, Vb);
  attn<<<dim3(32, 12, 2), 128, 0, stream>>>(Qb, Kb, Vb, O, L);
  normalize<<<dim3((S_LEN * HID / 4) / 256), 256, 0, stream>>>(O, L);
}

// Round 5
// 211.931 us; speedup vs baseline: 1.1280x; 1.1280x over previous
//
#include <hip/hip_runtime.h>
#include <hip/hip_bf16.h>

#define S_LEN 4096
#define HID   768
#define NH    12
#define HD    64

typedef __attribute__((ext_vector_type(8))) __bf16 bf16x8;
typedef __attribute__((ext_vector_type(4))) float  f32x4;

// round-to-nearest-even fp32 -> bf16
__device__ __forceinline__ unsigned short f2bf(float f) {
  union { float f; unsigned u; } v; v.f = f;
  unsigned r = v.u + 0x7fffu + ((v.u >> 16) & 1u);
  return (unsigned short)(r >> 16);
}

// pack two fp32 -> bf16x2 (low = first arg)
__device__ __forceinline__ unsigned pk2bf(float lo, float hi) {
  __hip_bfloat162 h = __float22bfloat162_rn(make_float2(lo, hi));
  union { __hip_bfloat162 h; unsigned u; } v; v.h = h;
  return v.u;
}

// ---------------------------------------------------------------------------
// Prep 1: X fp32 -> bf16
// ---------------------------------------------------------------------------
__global__ __launch_bounds__(256) void conv_x(const float* __restrict__ X,
                                              unsigned short* __restrict__ Xb)
{
  const int i = blockIdx.x * 256 + threadIdx.x;
  const float4 v = ((const float4*)X)[i];
  ushort4 o;
  o.x = f2bf(v.x); o.y = f2bf(v.y); o.z = f2bf(v.z); o.w = f2bf(v.w);
  ((ushort4*)Xb)[i] = o;
}

// ---------------------------------------------------------------------------
// Prep 2: W [k][n] fp32 -> Wt [n][k] bf16 (z = q/k/v)
// ---------------------------------------------------------------------------
__global__ __launch_bounds__(256) void conv_wt(
    const float* __restrict__ Wq, const float* __restrict__ Wk, const float* __restrict__ Wv,
    unsigned short* __restrict__ Wt)
{
  const int z = blockIdx.z;
  const float* W = (z == 0) ? Wq : (z == 1) ? Wk : Wv;
  unsigned short* O = Wt + (size_t)z * HID * HID;
  const int k0 = blockIdx.x * 64, n0 = blockIdx.y * 64;
  __shared__ unsigned short T[64][72];
  const int tid = threadIdx.x;
  #pragma unroll
  for (int i = tid; i < 512; i += 256) {
    const int kr = i >> 3, c8 = (i & 7) * 8;
    const float4 a = *(const float4*)&W[(size_t)(k0 + kr) * HID + n0 + c8];
    const float4 b = *(const float4*)&W[(size_t)(k0 + kr) * HID + n0 + c8 + 4];
    T[kr][c8 + 0] = f2bf(a.x); T[kr][c8 + 1] = f2bf(a.y);
    T[kr][c8 + 2] = f2bf(a.z); T[kr][c8 + 3] = f2bf(a.w);
    T[kr][c8 + 4] = f2bf(b.x); T[kr][c8 + 5] = f2bf(b.y);
    T[kr][c8 + 6] = f2bf(b.z); T[kr][c8 + 7] = f2bf(b.w);
  }
  __syncthreads();
  #pragma unroll
  for (int i = tid; i < 512; i += 256) {
    const int nr = i >> 3, c8 = (i & 7) * 8;
    ushort4 lo, hi;
    lo.x = T[c8 + 0][nr]; lo.y = T[c8 + 1][nr]; lo.z = T[c8 + 2][nr]; lo.w = T[c8 + 3][nr];
    hi.x = T[c8 + 4][nr]; hi.y = T[c8 + 5][nr]; hi.z = T[c8 + 6][nr]; hi.w = T[c8 + 7][nr];
    ushort4* dst = (ushort4*)&O[(size_t)(n0 + nr) * HID + k0 + c8];
    dst[0] = lo; dst[1] = hi;
  }
}

// ---------------------------------------------------------------------------
// Kernel 1: fused QKV projection. One WG = (head h, m-tile 64) computes the
// Q, K and V 64-col blocks together: X k-slab staged ONCE per iter for 24
// MFMAs (3x the MFMA/staging ratio of split kernels). XOR-swizzled LDS,
// register prefetch, LDS-restaged coalesced epilogue.
// Q pre-scaled by 0.125*log2(e) (exp2 softmax downstream).
// V written [h][d][s] with within-64-block permutation
// tau(s) = (s>>5)*32 + (s&15)*2 + ((s>>4)&1)  (matches attn's P layout).
// ---------------------------------------------------------------------------
__global__ __launch_bounds__(256) void qkv_fused(
    const unsigned short* __restrict__ Xb, const unsigned short* __restrict__ Wt,
    const float* __restrict__ bq, const float* __restrict__ bk, const float* __restrict__ bv,
    unsigned short* __restrict__ Qo, unsigned short* __restrict__ Ko, unsigned short* __restrict__ Vo)
{
  const int tid  = threadIdx.x;
  const int wave = tid >> 6;
  const int lane = tid & 63;
  const int g = lane >> 4, c = lane & 15;
  const int h  = blockIdx.x;          // head == n-tile (12)
  const int n0 = h * 64;
  const int m0 = blockIdx.y * 64;     // 64 m-tiles

  __shared__ unsigned short Xl[4096];       // [m][k] swizzled
  __shared__ unsigned short Wl[3][4096];    // [n][k] swizzled, per matrix

  f32x4 acc[3][4];
  #pragma unroll
  for (int z = 0; z < 3; ++z)
    #pragma unroll
    for (int nt = 0; nt < 4; ++nt) acc[z][nt] = (f32x4){0.f, 0.f, 0.f, 0.f};

  bf16x8 rx[2], rw[3][2];
  #pragma unroll
  for (int jj = 0; jj < 2; ++jj) {
    const int id = tid + 256 * jj, row = id >> 3, c8 = (id & 7) * 8;
    rx[jj] = *(const bf16x8*)&Xb[(size_t)(m0 + row) * HID + c8];
    #pragma unroll
    for (int z = 0; z < 3; ++z)
      rw[z][jj] = *(const bf16x8*)&Wt[(size_t)z * HID * HID + (size_t)(n0 + row) * HID + c8];
  }

  const int swz = (c & 7) * 8;

  for (int k0 = 0; k0 < HID; k0 += 64) {
    __syncthreads();
    #pragma unroll
    for (int jj = 0; jj < 2; ++jj) {
      const int id = tid + 256 * jj, row = id >> 3, c8 = (id & 7) * 8;
      const int sc8 = c8 ^ ((row & 7) * 8);
      *(bf16x8*)&Xl[row * 64 + sc8] = rx[jj];
      #pragma unroll
      for (int z = 0; z < 3; ++z)
        *(bf16x8*)&Wl[z][row * 64 + sc8] = rw[z][jj];
    }
    __syncthreads();

    if (k0 + 64 < HID) {   // prefetch next k-slab; lands during the 24 MFMAs
      const int kk = k0 + 64;
      #pragma unroll
      for (int jj = 0; jj < 2; ++jj) {
        const int id = tid + 256 * jj, row = id >> 3, c8 = (id & 7) * 8;
        rx[jj] = *(const bf16x8*)&Xb[(size_t)(m0 + row) * HID + kk + c8];
        #pragma unroll
        for (int z = 0; z < 3; ++z)
          rw[z][jj] = *(const bf16x8*)&Wt[(size_t)z * HID * HID + (size_t)(n0 + row) * HID + kk + c8];
      }
    }

    const bf16x8 a0 = *(const bf16x8*)&Xl[(wave * 16 + c) * 64 + ((g * 8) ^ swz)];
    const bf16x8 a1 = *(const bf16x8*)&Xl[(wave * 16 + c) * 64 + ((32 + g * 8) ^ swz)];
    #pragma unroll
    for (int z = 0; z < 3; ++z) {
      #pragma unroll
      for (int nt = 0; nt < 4; ++nt) {
        const bf16x8 b0 = *(const bf16x8*)&Wl[z][(nt * 16 + c) * 64 + ((g * 8) ^ swz)];
        const bf16x8 b1 = *(const bf16x8*)&Wl[z][(nt * 16 + c) * 64 + ((32 + g * 8) ^ swz)];
        acc[z][nt] = __builtin_amdgcn_mfma_f32_16x16x32_bf16(a0, b0, acc[z][nt], 0, 0, 0);
        acc[z][nt] = __builtin_amdgcn_mfma_f32_16x16x32_bf16(a1, b1, acc[z][nt], 0, 0, 0);
      }
    }
  }

  // epilogue: per matrix, restage through Xl (swizzled) -> coalesced b128 stores
  #pragma unroll
  for (int z = 0; z < 3; ++z) {
    const float* bias = (z == 0) ? bq : (z == 1) ? bk : bv;
    unsigned short* Out = (z == 0) ? Qo : (z == 1) ? Ko : Vo;
    const float qsc = (z == 0) ? 0.1803368782f : 1.0f;   // 0.125 * log2(e)
    __syncthreads();
    #pragma unroll
    for (int nt = 0; nt < 4; ++nt) {
      const float bv_ = bias[n0 + nt * 16 + c];
      #pragma unroll
      for (int r = 0; r < 4; ++r) {
        const unsigned short val = f2bf((acc[z][nt][r] + bv_) * qsc);
        if (z == 2) {
          // Xl[d][tau(s_local)]; s_local = wave*16 + 4g + r
          const int row = nt * 16 + c;
          const int col = (wave >> 1) * 32 + (4 * g + r) * 2 + (wave & 1);
          Xl[row * 64 + (col ^ ((row & 7) * 8))] = val;
        } else {
          const int row = wave * 16 + 4 * g + r;
          const int col = nt * 16 + c;
          Xl[row * 64 + (col ^ ((row & 7) * 8))] = val;
        }
      }
    }
    __syncthreads();
    #pragma unroll
    for (int jj = 0; jj < 2; ++jj) {
      const int j = tid + 256 * jj, row = j >> 3, c8 = (j & 7) * 8;
      const bf16x8 v = *(const bf16x8*)&Xl[row * 64 + (c8 ^ ((row & 7) * 8))];
      if (z == 2)
        *(bf16x8*)&Out[((size_t)h * HD + row) * S_LEN + m0 + c8] = v;   // [h][d][s-perm]
      else
        *(bf16x8*)&Out[((size_t)h * S_LEN + m0 + row) * HD + c8] = v;   // [h][s][d]
    }
  }
}

// ---------------------------------------------------------------------------
// Kernel 2: attention. Round-3 shape (4 waves x 32 q-rows = 128 q/WG,
// KV-split 2 -> 768 WGs) + swizzled unpadded LDS (0 conflicts) + exp2
// no-max softmax (Q pre-scaled by log2e/8) + packed b32 P stores (tau
// permutation, matched by V layout) + K/V register prefetch.
// Denominator via ones-column MFMA; partials atomicAdd'ed (2 per element).
// LDS 32 KB -> 5 WGs/CU.
// ---------------------------------------------------------------------------
__global__ __launch_bounds__(256) void attn(
    const unsigned short* __restrict__ Q, const unsigned short* __restrict__ K,
    const unsigned short* __restrict__ Vp,   // [h][d][s-perm]
    float* __restrict__ O, float* __restrict__ L)
{
  const int qt = blockIdx.x;   // 0..31
  const int h  = blockIdx.y;   // 0..11
  const int sp = blockIdx.z;   // 0..1
  const int tid  = threadIdx.x;
  const int wave = tid >> 6;
  const int lane = tid & 63;
  const int g = lane >> 4, c = lane & 15;
  const int q0 = qt * 128;
  const int k_base = sp * 2048;

  __shared__ unsigned short Kl[4096];      // [key][d] swizzled
  __shared__ unsigned short Vt[4096];      // [d][key-perm] swizzled
  __shared__ unsigned short Pl[4][2048];   // per-wave P [32 q][64 key-perm] swizzled
  unsigned short* PlFlat = &Pl[0][0];      // doubles as Q staging [128][64]

  const int swz = (c & 7) * 8;

  // stage Q tile (128x64 = 16 KB) into the P region, swizzled
  #pragma unroll
  for (int i = tid; i < 1024; i += 256) {
    const int row = i >> 3, c8 = (i & 7) * 8;
    *(bf16x8*)&PlFlat[row * 64 + (c8 ^ ((row & 7) * 8))] =
        *(const bf16x8*)&Q[((size_t)h * S_LEN + q0 + row) * HD + c8];
  }
  __syncthreads();

  // Q A-frags (rows wave*32 + s*16 + c; row&7 == c&7 so swz matches)
  bf16x8 aq[2][2];
  #pragma unroll
  for (int s = 0; s < 2; ++s) {
    const int row = wave * 32 + s * 16 + c;
    aq[s][0] = *(const bf16x8*)&PlFlat[row * 64 + ((g * 8) ^ swz)];
    aq[s][1] = *(const bf16x8*)&PlFlat[row * 64 + ((32 + g * 8) ^ swz)];
  }

  bf16x8 bones;   // B column 0 = 1.0 -> C[:,0] = row sums
  {
    const unsigned short one_bf = (c == 0) ? 0x3F80u : 0u;
    #pragma unroll
    for (int j = 0; j < 8; ++j) ((unsigned short*)&bones)[j] = one_bf;
  }

  f32x4 o[2][4];
  #pragma unroll
  for (int s = 0; s < 2; ++s)
    #pragma unroll
    for (int nt = 0; nt < 4; ++nt) o[s][nt] = (f32x4){0.f, 0.f, 0.f, 0.f};
  f32x4 lacc[2] = {{0.f,0.f,0.f,0.f},{0.f,0.f,0.f,0.f}};

  unsigned short* P = Pl[wave];

  // prefetch tile 0 into registers
  bf16x8 rk[2], rv[2];
  #pragma unroll
  for (int jj = 0; jj < 2; ++jj) {
    const int j = tid + 256 * jj, row = j >> 3, c8 = (j & 7) * 8;
    rk[jj] = *(const bf16x8*)&K[((size_t)h * S_LEN + k_base + row) * HD + c8];
    rv[jj] = *(const bf16x8*)&Vp[((size_t)h * HD + row) * S_LEN + k_base + c8];
  }

  for (int kt = 0; kt < 32; ++kt) {
    __syncthreads();   // prev frag reads + (first iter) Q-frag reads done
    #pragma unroll
    for (int jj = 0; jj < 2; ++jj) {
      const int j = tid + 256 * jj, row = j >> 3, c8 = (j & 7) * 8;
      const int sc8 = c8 ^ ((row & 7) * 8);
      *(bf16x8*)&Kl[row * 64 + sc8] = rk[jj];
      *(bf16x8*)&Vt[row * 64 + sc8] = rv[jj];
    }
    __syncthreads();

    if (kt + 1 < 32) {   // prefetch next tile; lands during compute below
      const int kb = k_base + (kt + 1) * 64;
      #pragma unroll
      for (int jj = 0; jj < 2; ++jj) {
        const int j = tid + 256 * jj, row = j >> 3, c8 = (j & 7) * 8;
        rk[jj] = *(const bf16x8*)&K[((size_t)h * S_LEN + kb + row) * HD + c8];
        rv[jj] = *(const bf16x8*)&Vp[((size_t)h * HD + row) * S_LEN + kb + c8];
      }
    }

    // QK^T in nt-pairs; exp2 + b32 packed P stores (tau: key nt*16+c -> pos (nt>>1)*32+2c+(nt&1))
    #pragma unroll
    for (int pr = 0; pr < 2; ++pr) {
      f32x4 sc[2][2];
      #pragma unroll
      for (int ntl = 0; ntl < 2; ++ntl) {
        const int nt = pr * 2 + ntl;
        const bf16x8 b0 = *(const bf16x8*)&Kl[(nt * 16 + c) * 64 + ((g * 8) ^ swz)];
        const bf16x8 b1 = *(const bf16x8*)&Kl[(nt * 16 + c) * 64 + ((32 + g * 8) ^ swz)];
        #pragma unroll
        for (int s = 0; s < 2; ++s) {
          f32x4 z = {0.f, 0.f, 0.f, 0.f};
          z = __builtin_amdgcn_mfma_f32_16x16x32_bf16(aq[s][0], b0, z, 0, 0, 0);
          z = __builtin_amdgcn_mfma_f32_16x16x32_bf16(aq[s][1], b1, z, 0, 0, 0);
          sc[ntl][s] = z;
        }
      }
      #pragma unroll
      for (int s = 0; s < 2; ++s) {
        #pragma unroll
        for (int r = 0; r < 4; ++r) {
          const unsigned u = pk2bf(exp2f(sc[0][s][r]), exp2f(sc[1][s][r]));
          const int row = s * 16 + 4 * g + r;
          const int col = pr * 32 + 2 * c;
          *(unsigned*)&P[row * 64 + (col ^ ((row & 7) * 8))] = u;
        }
      }
    }

    // P A-frags (same-wave write->read; compiler orders via lgkmcnt)
    bf16x8 ap[2][2];
    #pragma unroll
    for (int s = 0; s < 2; ++s) {
      const int row = s * 16 + c;
      ap[s][0] = *(const bf16x8*)&P[row * 64 + ((g * 8) ^ swz)];
      ap[s][1] = *(const bf16x8*)&P[row * 64 + ((32 + g * 8) ^ swz)];
    }
    #pragma unroll
    for (int nt = 0; nt < 4; ++nt) {
      const bf16x8 b0 = *(const bf16x8*)&Vt[(nt * 16 + c) * 64 + ((g * 8) ^ swz)];
      const bf16x8 b1 = *(const bf16x8*)&Vt[(nt * 16 + c) * 64 + ((32 + g * 8) ^ swz)];
      #pragma unroll
      for (int s = 0; s < 2; ++s) {
        o[s][nt] = __builtin_amdgcn_mfma_f32_16x16x32_bf16(ap[s][0], b0, o[s][nt], 0, 0, 0);
        o[s][nt] = __builtin_amdgcn_mfma_f32_16x16x32_bf16(ap[s][1], b1, o[s][nt], 0, 0, 0);
      }
    }
    #pragma unroll
    for (int s = 0; s < 2; ++s) {
      lacc[s] = __builtin_amdgcn_mfma_f32_16x16x32_bf16(ap[s][0], bones, lacc[s], 0, 0, 0);
      lacc[s] = __builtin_amdgcn_mfma_f32_16x16x32_bf16(ap[s][1], bones, lacc[s], 0, 0, 0);
    }
  }

  // epilogue: accumulate partials (exactly 2 contributions per element)
  #pragma unroll
  for (int s = 0; s < 2; ++s) {
    #pragma unroll
    for (int nt = 0; nt < 4; ++nt) {
      #pragma unroll
      for (int r = 0; r < 4; ++r) {
        const int row = q0 + wave * 32 + s * 16 + 4 * g + r;
        atomicAdd(&O[(size_t)row * HID + h * HD + nt * 16 + c], o[s][nt][r]);
      }
    }
  }
  if (c == 0) {
    #pragma unroll
    for (int s = 0; s < 2; ++s)
      #pragma unroll
      for (int r = 0; r < 4; ++r)
        atomicAdd(&L[h * S_LEN + q0 + wave * 32 + s * 16 + 4 * g + r], lacc[s][r]);
  }
}

// ---------------------------------------------------------------------------
// Kernel 3: normalize O by softmax denominator
// ---------------------------------------------------------------------------
__global__ __launch_bounds__(256) void normalize(float* __restrict__ O,
                                                 const float* __restrict__ L)
{
  const int i = blockIdx.x * 256 + threadIdx.x;
  float4 v = ((const float4*)O)[i];
  const int idx4 = i * 4;
  const int row = idx4 / HID;
  const int h   = (idx4 % HID) >> 6;
  const float inv = 1.0f / L[h * S_LEN + row];
  v.x *= inv; v.y *= inv; v.z *= inv; v.w *= inv;
  ((float4*)O)[i] = v;
}

// ---------------------------------------------------------------------------
extern "C" void kernel_launch(void* const* d_in, const int* in_sizes, int n_in,
                              void* d_out, int out_size, void* d_ws, size_t ws_size,
                              hipStream_t stream) {
  const float* X  = (const float*)d_in[0];
  const float* Wq = (const float*)d_in[1];
  const float* bq = (const float*)d_in[2];
  const float* Wk = (const float*)d_in[3];
  const float* bk = (const float*)d_in[4];
  const float* Wv = (const float*)d_in[5];
  const float* bv = (const float*)d_in[6];

  unsigned short* Xb = (unsigned short*)d_ws;
  unsigned short* Wt = Xb + (size_t)S_LEN * HID;
  unsigned short* Qb = Wt + (size_t)3 * HID * HID;
  unsigned short* Kb = Qb + (size_t)NH * S_LEN * HD;
  unsigned short* Vb = Kb + (size_t)NH * S_LEN * HD;
  float* L = (float*)(Vb + (size_t)NH * S_LEN * HD);
  float* O = (float*)d_out;

  hipMemsetAsync(O, 0, (size_t)S_LEN * HID * sizeof(float), stream);
  hipMemsetAsync(L, 0, (size_t)NH * S_LEN * sizeof(float), stream);

  conv_x <<<dim3((S_LEN * HID / 4) / 256), 256, 0, stream>>>(X, Xb);
  conv_wt<<<dim3(12, 12, 3), 256, 0, stream>>>(Wq, Wk, Wv, Wt);
  qkv_fused<<<dim3(12, 64), 256, 0, stream>>>(Xb, Wt, bq, bk, bv, Qb, Kb, Vb);
  attn<<<dim3(32, 12, 2), 256, 0, stream>>>(Qb, Kb, Vb, O, L);
  normalize<<<dim3((S_LEN * HID / 4) / 256), 256, 0, stream>>>(O, L);
}